// Round 2
// baseline (613.254 us; speedup 1.0000x reference)
//
#include <hip/hip_runtime.h>

#define NN 50000
#define NE 500000
#define HD 128
#define HD2 256
#define NL 4
#define NG 1000

constexpr float MSG_EPS = 1e-7f;
constexpr float LNEPS   = 1e-5f;

typedef float  f32x4  __attribute__((ext_vector_type(4)));
typedef __bf16 bf16x8 __attribute__((ext_vector_type(8)));

__device__ __forceinline__ unsigned short f2b(float f) {
    unsigned int u = __float_as_uint(f);
    unsigned int r = u + 0x7FFFu + ((u >> 16) & 1u);
    return (unsigned short)(r >> 16);
}
__device__ __forceinline__ float b2f(unsigned short h) {
    return __uint_as_float(((unsigned int)h) << 16);
}
__device__ __forceinline__ unsigned int pack2(float a, float b) {
    return (unsigned int)f2b(a) | ((unsigned int)f2b(b) << 16);
}

// ---------------- node encoder: z0 = bf16(x @ Wn + bn) ----------------
__global__ void k_encode_nodes(const float* __restrict__ x, const float* __restrict__ W,
                               const float* __restrict__ b, unsigned short* __restrict__ zb) {
    int n = blockIdx.x;
    int c = threadIdx.x;  // 128
    float xr[9];
#pragma unroll
    for (int k = 0; k < 9; k++) xr[k] = x[n * 9 + k];
    float acc = b[c];
#pragma unroll
    for (int k = 0; k < 9; k++) acc = fmaf(xr[k], W[k * HD + c], acc);
    zb[n * HD + c] = f2b(acc);
}

// ---------------- weight prep: fp32 -> bf16 transposed ----------------
__global__ void k_prep(const float* __restrict__ W1, const float* __restrict__ W2,
                       unsigned short* __restrict__ W1T, unsigned short* __restrict__ W2T) {
    int idx = blockIdx.x * 256 + threadIdx.x;  // 131072 total
    {
        int k = idx & 127, n = (idx >> 7) & 255, l = idx >> 15;
        W1T[idx] = f2b(W1[(l * 128 + k) * 256 + n]);
    }
    {
        int k = idx & 255, n = (idx >> 8) & 127, l = idx >> 15;
        W2T[idx] = f2b(W2[(l * 256 + k) * 128 + n]);
    }
}

// ---------------- CSR build ----------------
__global__ void k_hist(const int* __restrict__ dst, int* __restrict__ counts) {
    int e = blockIdx.x * blockDim.x + threadIdx.x;
    if (e < NE) atomicAdd(&counts[dst[e]], 1);
}

#define SCAN_B 512
__global__ void k_scan1(const int* __restrict__ counts, int* __restrict__ incl,
                        int* __restrict__ bsum) {
    __shared__ int s[SCAN_B];
    int i = blockIdx.x * SCAN_B + threadIdx.x;
    int v = (i < NN) ? counts[i] : 0;
    s[threadIdx.x] = v;
    __syncthreads();
    for (int off = 1; off < SCAN_B; off <<= 1) {
        int t = (threadIdx.x >= off) ? s[threadIdx.x - off] : 0;
        __syncthreads();
        s[threadIdx.x] += t;
        __syncthreads();
    }
    if (i < NN) incl[i] = s[threadIdx.x];
    if (threadIdx.x == SCAN_B - 1) bsum[blockIdx.x] = s[threadIdx.x];
}

__global__ void k_scan2(const int* __restrict__ bsum, int* __restrict__ boff, int nb) {
    __shared__ int s[128];
    int v = (threadIdx.x < nb) ? bsum[threadIdx.x] : 0;
    s[threadIdx.x] = v;
    __syncthreads();
    for (int off = 1; off < 128; off <<= 1) {
        int t = (threadIdx.x >= off) ? s[threadIdx.x - off] : 0;
        __syncthreads();
        s[threadIdx.x] += t;
        __syncthreads();
    }
    if (threadIdx.x < nb) boff[threadIdx.x] = s[threadIdx.x] - v;  // exclusive
}

__global__ void k_scan3(const int* __restrict__ incl, const int* __restrict__ boff,
                        int* __restrict__ row_start) {
    int i = blockIdx.x * SCAN_B + threadIdx.x;
    if (i < NN) row_start[i + 1] = incl[i] + boff[blockIdx.x];
    if (i == 0) row_start[0] = 0;
}

// pack {attr0, attr1, attr2, src} per CSR slot
__global__ void k_scatter(const int* __restrict__ src, const int* __restrict__ dst,
                          const float* __restrict__ eattr, const int* __restrict__ row_start,
                          int* __restrict__ cursor, float4* __restrict__ aperm) {
    int e = blockIdx.x * blockDim.x + threadIdx.x;
    if (e >= NE) return;
    int d = dst[e];
    int p = row_start[d] + atomicAdd(&cursor[d], 1);
    float4 v;
    v.x = eattr[e * 3 + 0];
    v.y = eattr[e * 3 + 1];
    v.z = eattr[e * 3 + 2];
    v.w = __int_as_float(src[e]);
    aperm[p] = v;
}

// ---------------- per-edge softmax-agg accumulate (2 channels/lane) ----------------
__device__ __forceinline__ void edge_acc2(float4 a, unsigned int zz, float2 w0, float2 w1,
                                          float2 w2, float2 bb, float tv, float& num0,
                                          float& num1, float& wm0, float& wm1) {
    float zx = b2f((unsigned short)zz), zy = b2f((unsigned short)(zz >> 16));
    float eax = fmaf(a.x, w0.x, fmaf(a.y, w1.x, fmaf(a.z, w2.x, bb.x)));
    float eay = fmaf(a.x, w0.y, fmaf(a.y, w1.y, fmaf(a.z, w2.y, bb.y)));
    float mx = fmaxf(zx + eax, 0.f) + MSG_EPS;
    float my = fmaxf(zy + eay, 0.f) + MSG_EPS;
    float ex = __expf(tv * mx), ey = __expf(tv * my);
    num0 += ex;
    num1 += ey;
    wm0 = fmaf(mx, ex, wm0);
    wm1 = fmaf(my, ey, wm1);
}

// ---------------- FUSED layer: softmax-agg -> LDS A-tile -> MLP -> h/zb ----------
// Per block (BM=32 nodes, 4 waves):
//   phase A: wave w aggregates nodes {nb+w+4k}, two nodes interleaved (2x gather MLP),
//            result (agg + zin_row) packed bf16x2 into LDS tile As (XOR-swizzled rows).
//   phase B: GEMM1 (A from LDS, W1T from L2) + in-register LN(256) + GEMM2 + epilogue
//            (residual h prefetched at entry, LN(128), h/zb stores) -- as verified k_mlp.
// zin is the PREVIOUS dispatch's output (stream-ordered, dispatch-boundary flush) so the
// random gather is race-free; zout != zin (ping-pong) so in-dispatch writes can't race.
#define BM 32
#define HS_LD 264   // bf16 row stride (256+8 shorts)
#define AS_W 68     // As/Ht row stride in uints (272 B, 16B-aligned rows)

__global__ __launch_bounds__(256) void k_layer(
    const unsigned short* __restrict__ zin, const float4* __restrict__ aperm,
    const int* __restrict__ row_start, const float* __restrict__ We,
    const float* __restrict__ be, const float* __restrict__ t, int layer,
    const unsigned short* __restrict__ W1T, const float* __restrict__ b1l,
    const float* __restrict__ lgl, const float* __restrict__ lbl,
    const unsigned short* __restrict__ W2T, const float* __restrict__ b2l,
    unsigned short* __restrict__ h, const float* __restrict__ gn,
    const float* __restrict__ bn, unsigned short* __restrict__ zout,
    int add_residual, int store_h) {
    __shared__ __align__(16) unsigned short Hs[BM * HS_LD];  // 16896 B
    __shared__ __align__(16) unsigned int AsHt[BM * AS_W];   // 8704 B (As, then Ht)
    __shared__ __align__(16) float2 st1[2][16][4];           // 1024 B

    int nb = blockIdx.x * BM;
    int tid = threadIdx.x;
    int w = tid >> 6, lane = tid & 63, q = lane >> 4, i = lane & 15;

    // ---- epilogue prefetch: residual h rows + final-LN params (hide under phases) ----
    unsigned int hv[8];
    const unsigned int* h32c = (const unsigned int*)h;
    if (add_residual) {
#pragma unroll
        for (int it = 0; it < 8; it++) {
            int row = nb + w + it * 4;
            hv[it] = (row < NN) ? h32c[(size_t)row * 64 + lane] : 0u;
        }
    } else {
#pragma unroll
        for (int it = 0; it < 8; it++) hv[it] = 0u;
    }
    float2 gg = *(const float2*)&gn[lane * 2];
    float2 cc = *(const float2*)&bn[lane * 2];

    // ================= phase A: softmax aggregation into As =================
    {
        int c = lane * 2;
        float2 w0 = *(const float2*)&We[c];
        float2 w1 = *(const float2*)&We[HD + c];
        float2 w2 = *(const float2*)&We[2 * HD + c];
        float2 bb = *(const float2*)&be[c];
        float tv = t[layer];
        const unsigned int* z32 = (const unsigned int*)zin;

#pragma unroll
        for (int m = 0; m < 4; m++) {
            int rrA = w + 8 * m, rrB = rrA + 4;
            int nA = nb + rrA, nB = nb + rrB;
            int sA0 = 0, sA1 = 0, sB0 = 0, sB1 = 0;
            if (nA < NN) { sA0 = row_start[nA]; sA1 = row_start[nA + 1]; }
            if (nB < NN) { sB0 = row_start[nB]; sB1 = row_start[nB + 1]; }
            float numA0 = 0.f, numA1 = 0.f, wmA0 = 0.f, wmA1 = 0.f;
            float numB0 = 0.f, numB1 = 0.f, wmB0 = 0.f, wmB1 = 0.f;
            int pa = sA0, pb = sB0;
            // dual-node interleaved main loop: 4 independent gathers in flight
            while (pa + 2 <= sA1 && pb + 2 <= sB1) {
                float4 eA0 = aperm[pa], eA1 = aperm[pa + 1];
                float4 eB0 = aperm[pb], eB1 = aperm[pb + 1];
                unsigned int gA0 = z32[(size_t)__float_as_int(eA0.w) * 64 + lane];
                unsigned int gA1 = z32[(size_t)__float_as_int(eA1.w) * 64 + lane];
                unsigned int gB0 = z32[(size_t)__float_as_int(eB0.w) * 64 + lane];
                unsigned int gB1 = z32[(size_t)__float_as_int(eB1.w) * 64 + lane];
                edge_acc2(eA0, gA0, w0, w1, w2, bb, tv, numA0, numA1, wmA0, wmA1);
                edge_acc2(eA1, gA1, w0, w1, w2, bb, tv, numA0, numA1, wmA0, wmA1);
                edge_acc2(eB0, gB0, w0, w1, w2, bb, tv, numB0, numB1, wmB0, wmB1);
                edge_acc2(eB1, gB1, w0, w1, w2, bb, tv, numB0, numB1, wmB0, wmB1);
                pa += 2;
                pb += 2;
            }
            // drain node A
            for (; pa + 4 <= sA1; pa += 4) {
                float4 e0 = aperm[pa], e1 = aperm[pa + 1], e2 = aperm[pa + 2],
                       e3 = aperm[pa + 3];
                unsigned int g0 = z32[(size_t)__float_as_int(e0.w) * 64 + lane];
                unsigned int g1 = z32[(size_t)__float_as_int(e1.w) * 64 + lane];
                unsigned int g2 = z32[(size_t)__float_as_int(e2.w) * 64 + lane];
                unsigned int g3 = z32[(size_t)__float_as_int(e3.w) * 64 + lane];
                edge_acc2(e0, g0, w0, w1, w2, bb, tv, numA0, numA1, wmA0, wmA1);
                edge_acc2(e1, g1, w0, w1, w2, bb, tv, numA0, numA1, wmA0, wmA1);
                edge_acc2(e2, g2, w0, w1, w2, bb, tv, numA0, numA1, wmA0, wmA1);
                edge_acc2(e3, g3, w0, w1, w2, bb, tv, numA0, numA1, wmA0, wmA1);
            }
            for (; pa < sA1; pa++) {
                float4 e0 = aperm[pa];
                unsigned int g0 = z32[(size_t)__float_as_int(e0.w) * 64 + lane];
                edge_acc2(e0, g0, w0, w1, w2, bb, tv, numA0, numA1, wmA0, wmA1);
            }
            // drain node B
            for (; pb + 4 <= sB1; pb += 4) {
                float4 e0 = aperm[pb], e1 = aperm[pb + 1], e2 = aperm[pb + 2],
                       e3 = aperm[pb + 3];
                unsigned int g0 = z32[(size_t)__float_as_int(e0.w) * 64 + lane];
                unsigned int g1 = z32[(size_t)__float_as_int(e1.w) * 64 + lane];
                unsigned int g2 = z32[(size_t)__float_as_int(e2.w) * 64 + lane];
                unsigned int g3 = z32[(size_t)__float_as_int(e3.w) * 64 + lane];
                edge_acc2(e0, g0, w0, w1, w2, bb, tv, numB0, numB1, wmB0, wmB1);
                edge_acc2(e1, g1, w0, w1, w2, bb, tv, numB0, numB1, wmB0, wmB1);
                edge_acc2(e2, g2, w0, w1, w2, bb, tv, numB0, numB1, wmB0, wmB1);
                edge_acc2(e3, g3, w0, w1, w2, bb, tv, numB0, numB1, wmB0, wmB1);
            }
            for (; pb < sB1; pb++) {
                float4 e0 = aperm[pb];
                unsigned int g0 = z32[(size_t)__float_as_int(e0.w) * 64 + lane];
                edge_acc2(e0, g0, w0, w1, w2, bb, tv, numB0, numB1, wmB0, wmB1);
            }
            // self term + swizzled LDS store (rows >= NN get zeros)
            {
                unsigned int vA = 0u, vB = 0u;
                if (nA < NN) {
                    unsigned int zn = z32[(size_t)nA * 64 + lane];
                    float ox = ((sA1 > sA0) ? (wmA0 / numA0) : 0.f) + b2f((unsigned short)zn);
                    float oy =
                        ((sA1 > sA0) ? (wmA1 / numA1) : 0.f) + b2f((unsigned short)(zn >> 16));
                    vA = pack2(ox, oy);
                }
                if (nB < NN) {
                    unsigned int zn = z32[(size_t)nB * 64 + lane];
                    float ox = ((sB1 > sB0) ? (wmB0 / numB0) : 0.f) + b2f((unsigned short)zn);
                    float oy =
                        ((sB1 > sB0) ? (wmB1 / numB1) : 0.f) + b2f((unsigned short)(zn >> 16));
                    vB = pack2(ox, oy);
                }
                AsHt[rrA * AS_W + (lane ^ ((rrA & 7) << 2))] = vA;
                AsHt[rrB * AS_W + (lane ^ ((rrB & 7) << 2))] = vB;
            }
        }
    }
    __syncthreads();

    // ================= phase B: GEMM1 (A from LDS) =================
    f32x4 acc[2][4];
#pragma unroll
    for (int rt = 0; rt < 2; rt++)
#pragma unroll
        for (int ct = 0; ct < 4; ct++) acc[rt][ct] = (f32x4){0.f, 0.f, 0.f, 0.f};

    bf16x8 bcur[4];
#pragma unroll
    for (int ct = 0; ct < 4; ct++)
        bcur[ct] = *(const bf16x8*)&W1T[(w * 64 + ct * 16 + i) * HD + q * 8];

    int sw = (i & 7) << 2;  // row XOR swizzle (rr&7 == i&7 for rows rt*16+i)
#pragma unroll
    for (int ks = 0; ks < 4; ks++) {
        bf16x8 bnxt[4];
        if (ks < 3) {
#pragma unroll
            for (int ct = 0; ct < 4; ct++)
                bnxt[ct] =
                    *(const bf16x8*)&W1T[(w * 64 + ct * 16 + i) * HD + (ks + 1) * 32 + q * 8];
        }
        bf16x8 av[2];
#pragma unroll
        for (int rt = 0; rt < 2; rt++) {
            int rr = rt * 16 + i;
            const char* p =
                (const char*)AsHt + rr * (AS_W * 4) + (((ks * 16 + q * 4) ^ sw) << 2);
            av[rt] = *(const bf16x8*)p;
        }
#pragma unroll
        for (int rt = 0; rt < 2; rt++)
#pragma unroll
            for (int ct = 0; ct < 4; ct++)
                acc[rt][ct] =
                    __builtin_amdgcn_mfma_f32_16x16x32_bf16(av[rt], bcur[ct], acc[rt][ct],
                                                            0, 0, 0);
        if (ks < 3) {
#pragma unroll
            for (int ct = 0; ct < 4; ct++) bcur[ct] = bnxt[ct];
        }
    }

    // ---- +b1 ----
#pragma unroll
    for (int ct = 0; ct < 4; ct++) {
        float bb = b1l[w * 64 + ct * 16 + i];
#pragma unroll
        for (int rt = 0; rt < 2; rt++)
#pragma unroll
            for (int r = 0; r < 4; r++) acc[rt][ct][r] += bb;
    }

    // ---- LN(256) stats in-register + cross-wave exchange ----
    {
        float sv[2][4], qv[2][4];
#pragma unroll
        for (int rt = 0; rt < 2; rt++)
#pragma unroll
            for (int r = 0; r < 4; r++) {
                float s = acc[rt][0][r] + acc[rt][1][r] + acc[rt][2][r] + acc[rt][3][r];
                float sq = 0.f;
#pragma unroll
                for (int ct = 0; ct < 4; ct++) sq = fmaf(acc[rt][ct][r], acc[rt][ct][r], sq);
                sv[rt][r] = s;
                qv[rt][r] = sq;
            }
#pragma unroll
        for (int m = 1; m <= 8; m <<= 1)
#pragma unroll
            for (int rt = 0; rt < 2; rt++)
#pragma unroll
                for (int r = 0; r < 4; r++) {
                    sv[rt][r] += __shfl_xor(sv[rt][r], m);
                    qv[rt][r] += __shfl_xor(qv[rt][r], m);
                }
        if (i == 0) {
#pragma unroll
            for (int rt = 0; rt < 2; rt++)
#pragma unroll
                for (int r = 0; r < 4; r++)
                    st1[rt][q * 4 + r][w] = make_float2(sv[rt][r], qv[rt][r]);
        }
    }
    __syncthreads();

    {
        float mu[2][4], inv[2][4];
#pragma unroll
        for (int rt = 0; rt < 2; rt++)
#pragma unroll
            for (int r = 0; r < 4; r++) {
                const float4* sp = (const float4*)&st1[rt][q * 4 + r][0];
                float4 a = sp[0], b = sp[1];
                float S = a.x + a.z + b.x + b.z;
                float Q = a.y + a.w + b.y + b.w;
                float m_ = S * (1.f / 256.f);
                float v_ = Q * (1.f / 256.f) - m_ * m_;
                mu[rt][r] = m_;
                inv[rt][r] = rsqrtf(v_ + LNEPS);
            }
#pragma unroll
        for (int ct = 0; ct < 4; ct++) {
            float g = lgl[w * 64 + ct * 16 + i];
            float c = lbl[w * 64 + ct * 16 + i];
#pragma unroll
            for (int rt = 0; rt < 2; rt++)
#pragma unroll
                for (int r = 0; r < 4; r++) {
                    float v =
                        fmaxf(fmaf((acc[rt][ct][r] - mu[rt][r]) * inv[rt][r], g, c), 0.f);
                    Hs[(rt * 16 + q * 4 + r) * HS_LD + w * 64 + ct * 16 + i] = f2b(v);
                }
        }
    }
    __syncthreads();

    // ---- GEMM2: 32x128, K=256; A from Hs, 1-step lookahead ----
    f32x4 acc2[2][2];
#pragma unroll
    for (int rt = 0; rt < 2; rt++)
#pragma unroll
        for (int ct = 0; ct < 2; ct++) acc2[rt][ct] = (f32x4){0.f, 0.f, 0.f, 0.f};

    bf16x8 hc[2], bc[2];
#pragma unroll
    for (int rt = 0; rt < 2; rt++) hc[rt] = *(const bf16x8*)&Hs[(rt * 16 + i) * HS_LD + q * 8];
#pragma unroll
    for (int ct = 0; ct < 2; ct++)
        bc[ct] = *(const bf16x8*)&W2T[(w * 32 + ct * 16 + i) * HD2 + q * 8];

#pragma unroll
    for (int ks = 0; ks < 8; ks++) {
        bf16x8 hn[2], bn2[2];
        if (ks < 7) {
#pragma unroll
            for (int rt = 0; rt < 2; rt++)
                hn[rt] = *(const bf16x8*)&Hs[(rt * 16 + i) * HS_LD + (ks + 1) * 32 + q * 8];
#pragma unroll
            for (int ct = 0; ct < 2; ct++)
                bn2[ct] =
                    *(const bf16x8*)&W2T[(w * 32 + ct * 16 + i) * HD2 + (ks + 1) * 32 + q * 8];
        }
#pragma unroll
        for (int rt = 0; rt < 2; rt++)
#pragma unroll
            for (int ct = 0; ct < 2; ct++)
                acc2[rt][ct] = __builtin_amdgcn_mfma_f32_16x16x32_bf16(hc[rt], bc[ct],
                                                                      acc2[rt][ct], 0, 0, 0);
        if (ks < 7) {
#pragma unroll
            for (int rt = 0; rt < 2; rt++) hc[rt] = hn[rt];
#pragma unroll
            for (int ct = 0; ct < 2; ct++) bc[ct] = bn2[ct];
        }
    }

    // ---- conv-out (+b2) -> bf16 LDS tile Ht (reuses As memory; As is dead) ----
    {
        unsigned short* Ht = (unsigned short*)AsHt;  // stride 2*AS_W shorts = 136
#pragma unroll
        for (int ct = 0; ct < 2; ct++) {
            float bb = b2l[w * 32 + ct * 16 + i];
#pragma unroll
            for (int rt = 0; rt < 2; rt++)
#pragma unroll
                for (int r = 0; r < 4; r++)
                    Ht[(rt * 16 + q * 4 + r) * (2 * AS_W) + w * 32 + ct * 16 + i] =
                        f2b(acc2[rt][ct][r] + bb);
        }
    }
    __syncthreads();

    // ---- row-wise COALESCED epilogue: residual (pre-fetched), h store, LN(128), zb ----
    {
        const unsigned int* Ht32 = AsHt;
        unsigned int* h32 = (unsigned int*)h;
        unsigned int* zb32 = (unsigned int*)zout;
#pragma unroll
        for (int it = 0; it < 8; it++) {
            int rr = w + it * 4;
            int row = nb + rr;
            unsigned int tv = Ht32[rr * AS_W + lane];
            float cx = b2f((unsigned short)tv) + b2f((unsigned short)hv[it]);
            float cy = b2f((unsigned short)(tv >> 16)) + b2f((unsigned short)(hv[it] >> 16));
            float s = cx + cy, sq = cx * cx + cy * cy;
#pragma unroll
            for (int m = 32; m >= 1; m >>= 1) {
                s += __shfl_xor(s, m);
                sq += __shfl_xor(sq, m);
            }
            float mu = s * (1.f / 128.f);
            float var = sq * (1.f / 128.f) - mu * mu;
            float inv = rsqrtf(var + LNEPS);
            float z0 = fmaxf(fmaf((cx - mu) * inv, gg.x, cc.x), 0.f);
            float z1 = fmaxf(fmaf((cy - mu) * inv, gg.y, cc.y), 0.f);
            if (row < NN) {
                if (store_h) h32[(size_t)row * 64 + lane] = pack2(cx, cy);
                zb32[(size_t)row * 64 + lane] = pack2(z0, z1);
            }
        }
    }
}

// ---------------- atomic-free global mean pool (batch is sorted) ----------------
__global__ void k_gbounds(const int* __restrict__ batch, int* __restrict__ gstart) {
    int g = blockIdx.x * blockDim.x + threadIdx.x;
    if (g > NG) return;
    int lo = 0, hi = NN;
    while (lo < hi) {
        int mid = (lo + hi) >> 1;
        if (batch[mid] < g) lo = mid + 1;
        else hi = mid;
    }
    gstart[g] = lo;
}

__global__ void k_pool(const unsigned short* __restrict__ zb, const int* __restrict__ gstart,
                       float* __restrict__ out) {
    int g = blockIdx.x;
    int c = threadIdx.x;  // 128
    int a = gstart[g], b = gstart[g + 1];
    float s0 = 0.f, s1 = 0.f;
    int n = a;
    for (; n + 2 <= b; n += 2) {
        s0 += b2f(zb[(size_t)n * HD + c]);
        s1 += b2f(zb[(size_t)(n + 1) * HD + c]);
    }
    if (n < b) s0 += b2f(zb[(size_t)n * HD + c]);
    out[g * HD + c] = (s0 + s1) / fmaxf((float)(b - a), 1.f);
}

// ---------------- launch ----------------
extern "C" void kernel_launch(void* const* d_in, const int* in_sizes, int n_in, void* d_out,
                              int out_size, void* d_ws, size_t ws_size, hipStream_t stream) {
    const float* x     = (const float*)d_in[0];
    const int* ei      = (const int*)d_in[1];
    const float* eattr = (const float*)d_in[2];
    const int* batch   = (const int*)d_in[3];
    const float* encW  = (const float*)d_in[4];
    const float* encB  = (const float*)d_in[5];
    const float* eW    = (const float*)d_in[6];
    const float* eB    = (const float*)d_in[7];
    const float* ln_g  = (const float*)d_in[8];
    const float* ln_b  = (const float*)d_in[9];
    const float* W1    = (const float*)d_in[10];
    const float* b1    = (const float*)d_in[11];
    const float* mlg   = (const float*)d_in[12];
    const float* mlb   = (const float*)d_in[13];
    const float* W2    = (const float*)d_in[14];
    const float* b2    = (const float*)d_in[15];
    const float* t     = (const float*)d_in[16];
    const int* src = ei;
    const int* dst = ei + NE;

    char* w = (char*)d_ws;
    auto alloc = [&](size_t bytes) {
        char* p = w;
        w += (bytes + 255) & ~size_t(255);
        return p;
    };
    unsigned short* h    = (unsigned short*)alloc(sizeof(unsigned short) * NN * HD);
    unsigned short* zbA  = (unsigned short*)alloc(sizeof(unsigned short) * NN * HD);
    unsigned short* zbB  = (unsigned short*)alloc(sizeof(unsigned short) * NN * HD);
    float4* aperm        = (float4*)alloc(sizeof(float4) * NE);
    int* row_start       = (int*)alloc(sizeof(int) * (NN + 1));
    int* counts          = (int*)alloc(sizeof(int) * NN);
    int* cursor          = (int*)alloc(sizeof(int) * NN);
    int* incl            = (int*)alloc(sizeof(int) * NN);
    int* bsum            = (int*)alloc(sizeof(int) * 128);
    int* boff            = (int*)alloc(sizeof(int) * 128);
    int* gstart          = (int*)alloc(sizeof(int) * (NG + 1));
    unsigned short* W1T  = (unsigned short*)alloc(sizeof(unsigned short) * NL * HD * HD2);
    unsigned short* W2T  = (unsigned short*)alloc(sizeof(unsigned short) * NL * HD2 * HD);

    hipMemsetAsync(counts, 0, sizeof(int) * NN, stream);
    hipMemsetAsync(cursor, 0, sizeof(int) * NN, stream);

    k_prep<<<512, 256, 0, stream>>>(W1, W2, W1T, W2T);
    k_encode_nodes<<<NN, HD, 0, stream>>>(x, encW, encB, zbA);
    k_hist<<<(NE + 255) / 256, 256, 0, stream>>>(dst, counts);
    int nsb = (NN + SCAN_B - 1) / SCAN_B;
    k_scan1<<<nsb, SCAN_B, 0, stream>>>(counts, incl, bsum);
    k_scan2<<<1, 128, 0, stream>>>(bsum, boff, nsb);
    k_scan3<<<nsb, SCAN_B, 0, stream>>>(incl, boff, row_start);
    k_scatter<<<(NE + 255) / 256, 256, 0, stream>>>(src, dst, eattr, row_start, cursor, aperm);
    k_gbounds<<<(NG + 256) / 256, 256, 0, stream>>>(batch, gstart);

    int nblk = (NN + BM - 1) / BM;
    for (int l = 0; l < NL; l++) {
        const unsigned short* zin = (l & 1) ? zbB : zbA;
        unsigned short* zout      = (l & 1) ? zbA : zbB;
        int ln_next = (l + 1) % NL;  // layer 3 fuses the final ln (reuses layer-0 params)
        k_layer<<<nblk, 256, 0, stream>>>(
            zin, aperm, row_start, eW, eB, t, l, W1T + (size_t)l * HD * HD2, b1 + l * HD2,
            mlg + l * HD2, mlb + l * HD2, W2T + (size_t)l * HD2 * HD, b2 + l * HD, h,
            ln_g + ln_next * HD, ln_b + ln_next * HD, zout, l > 0, l < NL - 1);
    }
    k_pool<<<NG, HD, 0, stream>>>(zbA, gstart, (float*)d_out);
}

// Round 3
// 490.308 us; speedup vs baseline: 1.2508x; 1.2508x over previous
//
#include <hip/hip_runtime.h>

#define NN 50000
#define NE 500000
#define HD 128
#define HD2 256
#define NL 4
#define NG 1000

constexpr float MSG_EPS = 1e-7f;
constexpr float LNEPS   = 1e-5f;

typedef float  f32x4  __attribute__((ext_vector_type(4)));
typedef __bf16 bf16x8 __attribute__((ext_vector_type(8)));

__device__ __forceinline__ unsigned short f2b(float f) {
    unsigned int u = __float_as_uint(f);
    unsigned int r = u + 0x7FFFu + ((u >> 16) & 1u);
    return (unsigned short)(r >> 16);
}
__device__ __forceinline__ float b2f(unsigned short h) {
    return __uint_as_float(((unsigned int)h) << 16);
}
__device__ __forceinline__ unsigned int pack2(float a, float b) {
    return (unsigned int)f2b(a) | ((unsigned int)f2b(b) << 16);
}

// ---------------- node encoder: z0 = bf16(x @ Wn + bn) ----------------
__global__ void k_encode_nodes(const float* __restrict__ x, const float* __restrict__ W,
                               const float* __restrict__ b, unsigned short* __restrict__ zb) {
    int n = blockIdx.x;
    int c = threadIdx.x;  // 128
    float xr[9];
#pragma unroll
    for (int k = 0; k < 9; k++) xr[k] = x[n * 9 + k];
    float acc = b[c];
#pragma unroll
    for (int k = 0; k < 9; k++) acc = fmaf(xr[k], W[k * HD + c], acc);
    zb[n * HD + c] = f2b(acc);
}

// ---------------- weight prep: fp32 -> bf16 transposed ----------------
__global__ void k_prep(const float* __restrict__ W1, const float* __restrict__ W2,
                       unsigned short* __restrict__ W1T, unsigned short* __restrict__ W2T) {
    int idx = blockIdx.x * 256 + threadIdx.x;  // 131072 total
    {
        int k = idx & 127, n = (idx >> 7) & 255, l = idx >> 15;
        W1T[idx] = f2b(W1[(l * 128 + k) * 256 + n]);
    }
    {
        int k = idx & 255, n = (idx >> 8) & 127, l = idx >> 15;
        W2T[idx] = f2b(W2[(l * 256 + k) * 128 + n]);
    }
}

// ---------------- CSR build ----------------
__global__ void k_hist(const int* __restrict__ dst, int* __restrict__ counts) {
    int e = blockIdx.x * blockDim.x + threadIdx.x;
    if (e < NE) atomicAdd(&counts[dst[e]], 1);
}

#define SCAN_B 512
__global__ void k_scan1(const int* __restrict__ counts, int* __restrict__ incl,
                        int* __restrict__ bsum) {
    __shared__ int s[SCAN_B];
    int i = blockIdx.x * SCAN_B + threadIdx.x;
    int v = (i < NN) ? counts[i] : 0;
    s[threadIdx.x] = v;
    __syncthreads();
    for (int off = 1; off < SCAN_B; off <<= 1) {
        int t = (threadIdx.x >= off) ? s[threadIdx.x - off] : 0;
        __syncthreads();
        s[threadIdx.x] += t;
        __syncthreads();
    }
    if (i < NN) incl[i] = s[threadIdx.x];
    if (threadIdx.x == SCAN_B - 1) bsum[blockIdx.x] = s[threadIdx.x];
}

__global__ void k_scan2(const int* __restrict__ bsum, int* __restrict__ boff, int nb) {
    __shared__ int s[128];
    int v = (threadIdx.x < nb) ? bsum[threadIdx.x] : 0;
    s[threadIdx.x] = v;
    __syncthreads();
    for (int off = 1; off < 128; off <<= 1) {
        int t = (threadIdx.x >= off) ? s[threadIdx.x - off] : 0;
        __syncthreads();
        s[threadIdx.x] += t;
        __syncthreads();
    }
    if (threadIdx.x < nb) boff[threadIdx.x] = s[threadIdx.x] - v;  // exclusive
}

__global__ void k_scan3(const int* __restrict__ incl, const int* __restrict__ boff,
                        int* __restrict__ row_start) {
    int i = blockIdx.x * SCAN_B + threadIdx.x;
    if (i < NN) row_start[i + 1] = incl[i] + boff[blockIdx.x];
    if (i == 0) row_start[0] = 0;
}

// pack {attr0, attr1, attr2, src<<6} per CSR slot (src premultiplied: z-row offset
// in uints, so the gather address is a single 32-bit add per edge)
__global__ void k_scatter(const int* __restrict__ src, const int* __restrict__ dst,
                          const float* __restrict__ eattr, const int* __restrict__ row_start,
                          int* __restrict__ cursor, float4* __restrict__ aperm) {
    int e = blockIdx.x * blockDim.x + threadIdx.x;
    if (e >= NE) return;
    int d = dst[e];
    int p = row_start[d] + atomicAdd(&cursor[d], 1);
    float4 v;
    v.x = eattr[e * 3 + 0];
    v.y = eattr[e * 3 + 1];
    v.z = eattr[e * 3 + 2];
    v.w = __int_as_float(src[e] << 6);
    aperm[p] = v;
}

// ---------------- per-edge softmax-agg accumulate (2 channels/lane) ----------------
__device__ __forceinline__ void edge_acc2(float4 a, unsigned int zz, float2 w0, float2 w1,
                                          float2 w2, float2 bb, float tv, float& num0,
                                          float& num1, float& wm0, float& wm1) {
    float zx = b2f((unsigned short)zz), zy = b2f((unsigned short)(zz >> 16));
    float eax = fmaf(a.x, w0.x, fmaf(a.y, w1.x, fmaf(a.z, w2.x, bb.x)));
    float eay = fmaf(a.x, w0.y, fmaf(a.y, w1.y, fmaf(a.z, w2.y, bb.y)));
    float mx = fmaxf(zx + eax, 0.f) + MSG_EPS;
    float my = fmaxf(zy + eay, 0.f) + MSG_EPS;
    float ex = __expf(tv * mx), ey = __expf(tv * my);
    num0 += ex;
    num1 += ey;
    wm0 = fmaf(mx, ex, wm0);
    wm1 = fmaf(my, ey, wm1);
}

// ---------------- softmax aggregation: one wave per node, 2 channels/lane ----------
// Software-pipelined edge loop: while the current 4-edge group's z-gathers are in
// flight, the NEXT group's aperm rows load (breaks the aperm->gather serial chain).
// Self-row z load hoisted above the loop (independent, hides under it).
__global__ __launch_bounds__(256) void k_aggregate(const unsigned short* __restrict__ zbin,
                                                   const float4* __restrict__ aperm,
                                                   const int* __restrict__ row_start,
                                                   const float* __restrict__ We,
                                                   const float* __restrict__ be,
                                                   const float* __restrict__ t, int layer,
                                                   unsigned int* __restrict__ outb) {
    int w = threadIdx.x >> 6, lane = threadIdx.x & 63;
    int n = blockIdx.x * 4 + w;
    if (n >= NN) return;
    int c = lane * 2;
    float2 w0 = *(const float2*)&We[c];
    float2 w1 = *(const float2*)&We[HD + c];
    float2 w2 = *(const float2*)&We[2 * HD + c];
    float2 bb = *(const float2*)&be[c];
    float tv = t[layer];
    int s0 = row_start[n], s1 = row_start[n + 1];
    const unsigned int* z32 = (const unsigned int*)zbin;
    unsigned int zn = z32[(size_t)n * 64 + lane];  // self row, early issue
    float num0 = 0.f, num1 = 0.f, wm0 = 0.f, wm1 = 0.f;
    int p = s0;
    if (p + 4 <= s1) {
        float4 A0 = aperm[p], A1 = aperm[p + 1], A2 = aperm[p + 2], A3 = aperm[p + 3];
        for (; p + 8 <= s1; p += 4) {
            unsigned int g0 = z32[(unsigned int)__float_as_int(A0.w) + lane];
            unsigned int g1 = z32[(unsigned int)__float_as_int(A1.w) + lane];
            unsigned int g2 = z32[(unsigned int)__float_as_int(A2.w) + lane];
            unsigned int g3 = z32[(unsigned int)__float_as_int(A3.w) + lane];
            float4 B0 = aperm[p + 4], B1 = aperm[p + 5], B2 = aperm[p + 6],
                   B3 = aperm[p + 7];
            edge_acc2(A0, g0, w0, w1, w2, bb, tv, num0, num1, wm0, wm1);
            edge_acc2(A1, g1, w0, w1, w2, bb, tv, num0, num1, wm0, wm1);
            edge_acc2(A2, g2, w0, w1, w2, bb, tv, num0, num1, wm0, wm1);
            edge_acc2(A3, g3, w0, w1, w2, bb, tv, num0, num1, wm0, wm1);
            A0 = B0;
            A1 = B1;
            A2 = B2;
            A3 = B3;
        }
        {  // last full group (guaranteed: p+4 <= s1 < p+8)
            unsigned int g0 = z32[(unsigned int)__float_as_int(A0.w) + lane];
            unsigned int g1 = z32[(unsigned int)__float_as_int(A1.w) + lane];
            unsigned int g2 = z32[(unsigned int)__float_as_int(A2.w) + lane];
            unsigned int g3 = z32[(unsigned int)__float_as_int(A3.w) + lane];
            edge_acc2(A0, g0, w0, w1, w2, bb, tv, num0, num1, wm0, wm1);
            edge_acc2(A1, g1, w0, w1, w2, bb, tv, num0, num1, wm0, wm1);
            edge_acc2(A2, g2, w0, w1, w2, bb, tv, num0, num1, wm0, wm1);
            edge_acc2(A3, g3, w0, w1, w2, bb, tv, num0, num1, wm0, wm1);
            p += 4;
        }
    }
    for (; p < s1; p++) {
        float4 a = aperm[p];
        unsigned int zz = z32[(unsigned int)__float_as_int(a.w) + lane];
        edge_acc2(a, zz, w0, w1, w2, bb, tv, num0, num1, wm0, wm1);
    }
    float ox = ((s1 > s0) ? (wm0 / num0) : 0.f) + b2f((unsigned short)zn);
    float oy = ((s1 > s0) ? (wm1 / num1) : 0.f) + b2f((unsigned short)(zn >> 16));
    outb[(size_t)n * 64 + lane] = pack2(ox, oy);
}

// ---------------- fused MFMA MLP + next-layer LN+relu ----------------
// hnew = (add? h : 0) + relu(LN(A@W1+b1))@W2+b2 ; h=bf16(hnew); zb=bf16(relu(LN_next(hnew)))
// BM=32, 4 waves. In-register LN1 stats (st1 LDS exchange).
// NEW: the FULL A tile (8 bf16x8 frags) is loaded at kernel entry -- all 8 outb round
// trips issue before anything else and overlap W1T streaming + h prefetch (GEMM1 then
// has zero exposed A latency). Residual h rows + epilogue LN params also prefetched.
#define BM 32
#define HS_LD 264  // bf16 row stride (256+8)
#define HT_LD 136  // bf16 row stride (128+8); as uint: 68

__global__ __launch_bounds__(256) void k_mlp(const unsigned short* __restrict__ outb,
                                             const unsigned short* __restrict__ W1T,
                                             const float* __restrict__ b1l,
                                             const float* __restrict__ lgl,
                                             const float* __restrict__ lbl,
                                             const unsigned short* __restrict__ W2T,
                                             const float* __restrict__ b2l,
                                             unsigned short* __restrict__ h,
                                             const float* __restrict__ gn,
                                             const float* __restrict__ bn,
                                             unsigned short* __restrict__ zb,
                                             int add_residual, int store_h) {
    __shared__ __align__(16) unsigned short Hs[BM * HS_LD];  // 16896 B
    __shared__ __align__(16) unsigned short Ht[BM * HT_LD];  // 8704 B
    __shared__ __align__(16) float2 st1[2][16][4];           // 1024 B

    int nb = blockIdx.x * BM;
    int tid = threadIdx.x;
    int w = tid >> 6, lane = tid & 63, q = lane >> 4, i = lane & 15;

    // ---- full A prefetch: all 8 fragments issue NOW (32 VGPR) ----
    bf16x8 areg[2][4];
#pragma unroll
    for (int rt = 0; rt < 2; rt++) {
        int row = nb + rt * 16 + i;
#pragma unroll
        for (int ks = 0; ks < 4; ks++)
            areg[rt][ks] = (row < NN)
                               ? *(const bf16x8*)&outb[(size_t)row * HD + ks * 32 + q * 8]
                               : (bf16x8)(__bf16)0.f;
    }

    // ---- epilogue prefetch: residual h rows + final-LN params ----
    unsigned int hv[8];
    const unsigned int* h32c = (const unsigned int*)h;
    if (add_residual) {
#pragma unroll
        for (int it = 0; it < 8; it++) {
            int row = nb + w + it * 4;
            hv[it] = (row < NN) ? h32c[(size_t)row * 64 + lane] : 0u;
        }
    } else {
#pragma unroll
        for (int it = 0; it < 8; it++) hv[it] = 0u;
    }
    float2 gg = *(const float2*)&gn[lane * 2];
    float2 cc = *(const float2*)&bn[lane * 2];

    // ---- GEMM1: 32x256, K=128; A in registers, B 1-step lookahead ----
    f32x4 acc[2][4];
#pragma unroll
    for (int rt = 0; rt < 2; rt++)
#pragma unroll
        for (int ct = 0; ct < 4; ct++) acc[rt][ct] = (f32x4){0.f, 0.f, 0.f, 0.f};

    bf16x8 bcur[4];
#pragma unroll
    for (int ct = 0; ct < 4; ct++)
        bcur[ct] = *(const bf16x8*)&W1T[(w * 64 + ct * 16 + i) * HD + q * 8];

#pragma unroll
    for (int ks = 0; ks < 4; ks++) {
        bf16x8 bnxt[4];
        if (ks < 3) {
#pragma unroll
            for (int ct = 0; ct < 4; ct++)
                bnxt[ct] =
                    *(const bf16x8*)&W1T[(w * 64 + ct * 16 + i) * HD + (ks + 1) * 32 + q * 8];
        }
#pragma unroll
        for (int rt = 0; rt < 2; rt++)
#pragma unroll
            for (int ct = 0; ct < 4; ct++)
                acc[rt][ct] = __builtin_amdgcn_mfma_f32_16x16x32_bf16(areg[rt][ks], bcur[ct],
                                                                     acc[rt][ct], 0, 0, 0);
        if (ks < 3) {
#pragma unroll
            for (int ct = 0; ct < 4; ct++) bcur[ct] = bnxt[ct];
        }
    }

    // ---- +b1 ----
#pragma unroll
    for (int ct = 0; ct < 4; ct++) {
        float bb = b1l[w * 64 + ct * 16 + i];
#pragma unroll
        for (int rt = 0; rt < 2; rt++)
#pragma unroll
            for (int r = 0; r < 4; r++) acc[rt][ct][r] += bb;
    }

    // ---- LN(256) stats in-register + cross-wave exchange ----
    {
        float sv[2][4], qv[2][4];
#pragma unroll
        for (int rt = 0; rt < 2; rt++)
#pragma unroll
            for (int r = 0; r < 4; r++) {
                float s = acc[rt][0][r] + acc[rt][1][r] + acc[rt][2][r] + acc[rt][3][r];
                float sq = 0.f;
#pragma unroll
                for (int ct = 0; ct < 4; ct++) sq = fmaf(acc[rt][ct][r], acc[rt][ct][r], sq);
                sv[rt][r] = s;
                qv[rt][r] = sq;
            }
#pragma unroll
        for (int m = 1; m <= 8; m <<= 1)
#pragma unroll
            for (int rt = 0; rt < 2; rt++)
#pragma unroll
                for (int r = 0; r < 4; r++) {
                    sv[rt][r] += __shfl_xor(sv[rt][r], m);
                    qv[rt][r] += __shfl_xor(qv[rt][r], m);
                }
        if (i == 0) {
#pragma unroll
            for (int rt = 0; rt < 2; rt++)
#pragma unroll
                for (int r = 0; r < 4; r++)
                    st1[rt][q * 4 + r][w] = make_float2(sv[rt][r], qv[rt][r]);
        }
    }
    __syncthreads();

    {
        float mu[2][4], inv[2][4];
#pragma unroll
        for (int rt = 0; rt < 2; rt++)
#pragma unroll
            for (int r = 0; r < 4; r++) {
                const float4* sp = (const float4*)&st1[rt][q * 4 + r][0];
                float4 a = sp[0], b = sp[1];
                float S = a.x + a.z + b.x + b.z;
                float Q = a.y + a.w + b.y + b.w;
                float m_ = S * (1.f / 256.f);
                float v_ = Q * (1.f / 256.f) - m_ * m_;
                mu[rt][r] = m_;
                inv[rt][r] = rsqrtf(v_ + LNEPS);
            }
#pragma unroll
        for (int ct = 0; ct < 4; ct++) {
            float g = lgl[w * 64 + ct * 16 + i];
            float c = lbl[w * 64 + ct * 16 + i];
#pragma unroll
            for (int rt = 0; rt < 2; rt++)
#pragma unroll
                for (int r = 0; r < 4; r++) {
                    float v =
                        fmaxf(fmaf((acc[rt][ct][r] - mu[rt][r]) * inv[rt][r], g, c), 0.f);
                    Hs[(rt * 16 + q * 4 + r) * HS_LD + w * 64 + ct * 16 + i] = f2b(v);
                }
        }
    }
    __syncthreads();

    // ---- GEMM2: 32x128, K=256; A from Hs, 1-step lookahead ----
    f32x4 acc2[2][2];
#pragma unroll
    for (int rt = 0; rt < 2; rt++)
#pragma unroll
        for (int ct = 0; ct < 2; ct++) acc2[rt][ct] = (f32x4){0.f, 0.f, 0.f, 0.f};

    bf16x8 hc[2], bc[2];
#pragma unroll
    for (int rt = 0; rt < 2; rt++) hc[rt] = *(const bf16x8*)&Hs[(rt * 16 + i) * HS_LD + q * 8];
#pragma unroll
    for (int ct = 0; ct < 2; ct++)
        bc[ct] = *(const bf16x8*)&W2T[(w * 32 + ct * 16 + i) * HD2 + q * 8];

#pragma unroll
    for (int ks = 0; ks < 8; ks++) {
        bf16x8 hn[2], bn2[2];
        if (ks < 7) {
#pragma unroll
            for (int rt = 0; rt < 2; rt++)
                hn[rt] = *(const bf16x8*)&Hs[(rt * 16 + i) * HS_LD + (ks + 1) * 32 + q * 8];
#pragma unroll
            for (int ct = 0; ct < 2; ct++)
                bn2[ct] =
                    *(const bf16x8*)&W2T[(w * 32 + ct * 16 + i) * HD2 + (ks + 1) * 32 + q * 8];
        }
#pragma unroll
        for (int rt = 0; rt < 2; rt++)
#pragma unroll
            for (int ct = 0; ct < 2; ct++)
                acc2[rt][ct] = __builtin_amdgcn_mfma_f32_16x16x32_bf16(hc[rt], bc[ct],
                                                                      acc2[rt][ct], 0, 0, 0);
        if (ks < 7) {
#pragma unroll
            for (int rt = 0; rt < 2; rt++) hc[rt] = hn[rt];
#pragma unroll
            for (int ct = 0; ct < 2; ct++) bc[ct] = bn2[ct];
        }
    }

    // ---- conv-out (+b2) -> bf16 LDS tile Ht (C-layout scatter; LDS absorbs it) ----
#pragma unroll
    for (int ct = 0; ct < 2; ct++) {
        float bb = b2l[w * 32 + ct * 16 + i];
#pragma unroll
        for (int rt = 0; rt < 2; rt++)
#pragma unroll
            for (int r = 0; r < 4; r++)
                Ht[(rt * 16 + q * 4 + r) * HT_LD + w * 32 + ct * 16 + i] =
                    f2b(acc2[rt][ct][r] + bb);
    }
    __syncthreads();

    // ---- row-wise COALESCED epilogue: residual (pre-fetched), h store, LN(128), zb ----
    {
        const unsigned int* Ht32 = (const unsigned int*)Ht;
        unsigned int* h32 = (unsigned int*)h;
        unsigned int* zb32 = (unsigned int*)zb;
#pragma unroll
        for (int it = 0; it < 8; it++) {
            int rr = w + it * 4;
            int row = nb + rr;
            unsigned int tv = Ht32[rr * (HT_LD / 2) + lane];
            float cx = b2f((unsigned short)tv) + b2f((unsigned short)hv[it]);
            float cy = b2f((unsigned short)(tv >> 16)) + b2f((unsigned short)(hv[it] >> 16));
            float s = cx + cy, sq = cx * cx + cy * cy;
#pragma unroll
            for (int m = 32; m >= 1; m >>= 1) {
                s += __shfl_xor(s, m);
                sq += __shfl_xor(sq, m);
            }
            float mu = s * (1.f / 128.f);
            float var = sq * (1.f / 128.f) - mu * mu;
            float inv = rsqrtf(var + LNEPS);
            float z0 = fmaxf(fmaf((cx - mu) * inv, gg.x, cc.x), 0.f);
            float z1 = fmaxf(fmaf((cy - mu) * inv, gg.y, cc.y), 0.f);
            if (row < NN) {
                if (store_h) h32[(size_t)row * 64 + lane] = pack2(cx, cy);
                zb32[(size_t)row * 64 + lane] = pack2(z0, z1);
            }
        }
    }
}

// ---------------- atomic-free global mean pool (batch is sorted) ----------------
__global__ void k_gbounds(const int* __restrict__ batch, int* __restrict__ gstart) {
    int g = blockIdx.x * blockDim.x + threadIdx.x;
    if (g > NG) return;
    int lo = 0, hi = NN;
    while (lo < hi) {
        int mid = (lo + hi) >> 1;
        if (batch[mid] < g) lo = mid + 1;
        else hi = mid;
    }
    gstart[g] = lo;
}

__global__ void k_pool(const unsigned short* __restrict__ zb, const int* __restrict__ gstart,
                       float* __restrict__ out) {
    int g = blockIdx.x;
    int c = threadIdx.x;  // 128
    int a = gstart[g], b = gstart[g + 1];
    float s0 = 0.f, s1 = 0.f;
    int n = a;
    for (; n + 2 <= b; n += 2) {
        s0 += b2f(zb[(size_t)n * HD + c]);
        s1 += b2f(zb[(size_t)(n + 1) * HD + c]);
    }
    if (n < b) s0 += b2f(zb[(size_t)n * HD + c]);
    out[g * HD + c] = (s0 + s1) / fmaxf((float)(b - a), 1.f);
}

// ---------------- launch ----------------
extern "C" void kernel_launch(void* const* d_in, const int* in_sizes, int n_in, void* d_out,
                              int out_size, void* d_ws, size_t ws_size, hipStream_t stream) {
    const float* x     = (const float*)d_in[0];
    const int* ei      = (const int*)d_in[1];
    const float* eattr = (const float*)d_in[2];
    const int* batch   = (const int*)d_in[3];
    const float* encW  = (const float*)d_in[4];
    const float* encB  = (const float*)d_in[5];
    const float* eW    = (const float*)d_in[6];
    const float* eB    = (const float*)d_in[7];
    const float* ln_g  = (const float*)d_in[8];
    const float* ln_b  = (const float*)d_in[9];
    const float* W1    = (const float*)d_in[10];
    const float* b1    = (const float*)d_in[11];
    const float* mlg   = (const float*)d_in[12];
    const float* mlb   = (const float*)d_in[13];
    const float* W2    = (const float*)d_in[14];
    const float* b2    = (const float*)d_in[15];
    const float* t     = (const float*)d_in[16];
    const int* src = ei;
    const int* dst = ei + NE;

    char* w = (char*)d_ws;
    auto alloc = [&](size_t bytes) {
        char* p = w;
        w += (bytes + 255) & ~size_t(255);
        return p;
    };
    unsigned short* h    = (unsigned short*)alloc(sizeof(unsigned short) * NN * HD);
    unsigned short* zb   = (unsigned short*)alloc(sizeof(unsigned short) * NN * HD);
    unsigned int* outb   = (unsigned int*)alloc(sizeof(unsigned int) * NN * HD / 2);
    float4* aperm        = (float4*)alloc(sizeof(float4) * NE);
    int* row_start       = (int*)alloc(sizeof(int) * (NN + 1));
    int* counts          = (int*)alloc(sizeof(int) * NN);
    int* cursor          = (int*)alloc(sizeof(int) * NN);
    int* incl            = (int*)alloc(sizeof(int) * NN);
    int* bsum            = (int*)alloc(sizeof(int) * 128);
    int* boff            = (int*)alloc(sizeof(int) * 128);
    int* gstart          = (int*)alloc(sizeof(int) * (NG + 1));
    unsigned short* W1T  = (unsigned short*)alloc(sizeof(unsigned short) * NL * HD * HD2);
    unsigned short* W2T  = (unsigned short*)alloc(sizeof(unsigned short) * NL * HD2 * HD);

    hipMemsetAsync(counts, 0, sizeof(int) * NN, stream);
    hipMemsetAsync(cursor, 0, sizeof(int) * NN, stream);

    k_prep<<<512, 256, 0, stream>>>(W1, W2, W1T, W2T);
    k_encode_nodes<<<NN, HD, 0, stream>>>(x, encW, encB, zb);
    k_hist<<<(NE + 255) / 256, 256, 0, stream>>>(dst, counts);
    int nsb = (NN + SCAN_B - 1) / SCAN_B;
    k_scan1<<<nsb, SCAN_B, 0, stream>>>(counts, incl, bsum);
    k_scan2<<<1, 128, 0, stream>>>(bsum, boff, nsb);
    k_scan3<<<nsb, SCAN_B, 0, stream>>>(incl, boff, row_start);
    k_scatter<<<(NE + 255) / 256, 256, 0, stream>>>(src, dst, eattr, row_start, cursor, aperm);
    k_gbounds<<<(NG + 256) / 256, 256, 0, stream>>>(batch, gstart);

    for (int l = 0; l < NL; l++) {
        k_aggregate<<<(NN + 3) / 4, 256, 0, stream>>>(zb, aperm, row_start, eW, eB, t, l, outb);
        int ln_next = (l + 1) % NL;  // layer 3 fuses the final ln (reuses layer-0 params)
        k_mlp<<<(NN + BM - 1) / BM, 256, 0, stream>>>(
            (const unsigned short*)outb, W1T + (size_t)l * HD * HD2, b1 + l * HD2,
            mlg + l * HD2, mlb + l * HD2, W2T + (size_t)l * HD2 * HD, b2 + l * HD, h,
            ln_g + ln_next * HD, ln_b + ln_next * HD, zb, l > 0, l < NL - 1);
    }
    k_pool<<<NG, HD, 0, stream>>>(zb, gstart, (float*)d_out);
}